// Round 12
// baseline (38.214 us; speedup 1.0000x reference)
//
#include <hip/hip_runtime.h>
#include <hip/hip_bf16.h>

// TiedCirculantSpectralFilter: B=512, D=1024, P=64, K=16, L_S=16
// Gram G[m,n] = sum_d gamma_d X[d,m] X[d,n] / 64 via bf16 MFMA,
// then 16 steps: hp <- hp - (1/16) A hp ; hk <- hk + (1/16) C hp.
//
// r9 champion structure (320 thr / 5 waves, lockstep, 2 barriers/chunk,
// issue distance 1) with the B-tile eliminated:
//  - stage ONE raw bf16 tile [80][64] per chunk
//  - B-fragments read rows 0-63 of the raw tile
//  - gamma folded into the A-fragment in registers. NOTE: store/read swizzle
//    cancels (involution), so the fragment's k indices are LINEAR:
//    k = ks*32 + (l>>4)*8 + 0..7. (r11 bug: had an extra ^fswz here.)

namespace {
typedef __attribute__((ext_vector_type(8))) short bf16x8;
typedef __attribute__((ext_vector_type(4))) float f32x4;
typedef __attribute__((ext_vector_type(4))) float fv4;
typedef __attribute__((ext_vector_type(2))) unsigned uv2;
typedef __attribute__((ext_vector_type(4))) unsigned uv4;

constexpr int kB  = 512;
constexpr int kD  = 1024;
constexpr int kP  = 64;
constexpr int kKK = 16;
constexpr int kLS = 16;
constexpr int kThreads = 320;           // 5 waves
constexpr int kKc = 64;                 // d-rows per chunk
constexpr int kNC = kD / kKc;           // 16 chunks

constexpr int ASZ = 80 * 128;           // raw X tile [80 m][64 k] bf16, swizzled
constexpr int GSTRIDE = 68;             // phase-2 G stride (floats)
constexpr int LDS_BYTES = 22528;        // max(2*ASZ=20480, 80*68*4+256=22016)

__device__ __forceinline__ unsigned bpack(float lo, float hi) {
  __hip_bfloat16 hl = __float2bfloat16(lo);
  __hip_bfloat16 hh = __float2bfloat16(hi);
  unsigned short ul, uh;
  __builtin_memcpy(&ul, &hl, 2);
  __builtin_memcpy(&uh, &hh, 2);
  return (unsigned)ul | ((unsigned)uh << 16);
}
__device__ __forceinline__ float blo(unsigned u) {
  return __builtin_bit_cast(float, u << 16);
}
__device__ __forceinline__ float bhi(unsigned u) {
  return __builtin_bit_cast(float, u & 0xffff0000u);
}

__global__ void __launch_bounds__(kThreads)
tcsf_kernel(const float* __restrict__ X, const float* __restrict__ y,
            const float* __restrict__ gamma, float* __restrict__ out) {
  __shared__ __align__(16) char smem[LDS_BYTES];

  const int t = threadIdx.x;
  const int b = blockIdx.x;
  const int l = t & 63;
  const int w = t >> 6;            // wave 0..4 -> m-rows 16w..16w+15

  float yv = 0.f;
  if (t < kP) yv = y[b * kP + t];

  const fv4* Xg = reinterpret_cast<const fv4*>(X) + (size_t)b * (kD * 80 / 4);

  // staging decomposition: thread t handles k = 4*kt + i (i=0..3), m = 4*ct + j
  const int ct = t % 20;           // m-quad
  const int kt = t / 20;           // k-quad (0..15)

  f32x4 acc[4];
#pragma unroll
  for (int nt = 0; nt < 4; ++nt) acc[nt] = (f32x4)(0.f);

  fv4 v0, v1, v2, v3;

  // ---- prologue: load + stage chunk 0 into buf 0 (raw only) ----
  {
    const int base = (4 * kt) * 20 + ct;
    v0 = Xg[base]; v1 = Xg[base + 20]; v2 = Xg[base + 40]; v3 = Xg[base + 60];
#pragma unroll
    for (int j = 0; j < 4; ++j) {
      const int m = 4 * ct + j;
      const int off = m * 128 + ((8 * kt) ^ ((m & 7) << 4));
      uv2 wa; wa.x = bpack(v0[j], v1[j]); wa.y = bpack(v2[j], v3[j]);
      *reinterpret_cast<uv2*>(smem + off) = wa;
    }
  }

  // fragment read addressing (constant per thread); rA&7 == rB&7 == l&7
  const int rA = 16 * w + (l & 15);
  const int colb = (l >> 4) * 16;
  const int fswz = (l & 7) << 4;
  // A-fragment k indices are LINEAR (swizzle cancels store<->read):
  const int kidx0 = colb >> 1;            // ks=0: k = (l>>4)*8
  const int kidx1 = (64 + colb) >> 1;     // ks=1: k = 32 + (l>>4)*8

  // ---- main loop over 16 chunks, double-buffered, 2 barriers/chunk ----
  for (int c = 0; c < kNC; ++c) {
    if (c + 1 < kNC) {  // issue next-chunk loads; latency hides under compute
      const int base = ((c + 1) * kKc + 4 * kt) * 20 + ct;
      v0 = Xg[base]; v1 = Xg[base + 20]; v2 = Xg[base + 40]; v3 = Xg[base + 60];
    }
    __syncthreads();  // buf[c&1] staging complete
    {
      const char* Tb = smem + (c & 1) * ASZ;
#pragma unroll
      for (int ks = 0; ks < 2; ++ks) {
        const int cb = ks * 64 + colb;
        // raw A fragment, then gamma-scale in registers
        const bf16x8 araw =
            *reinterpret_cast<const bf16x8*>(Tb + rA * 128 + (cb ^ fswz));
        const float* gp = gamma + c * kKc + (ks ? kidx1 : kidx0);
        const fv4 glo = *reinterpret_cast<const fv4*>(gp);
        const fv4 ghi = *reinterpret_cast<const fv4*>(gp + 4);
        uv4 au; __builtin_memcpy(&au, &araw, 16);
        uv4 ou;
        ou.x = bpack(blo(au.x) * glo[0], bhi(au.x) * glo[1]);
        ou.y = bpack(blo(au.y) * glo[2], bhi(au.y) * glo[3]);
        ou.z = bpack(blo(au.z) * ghi[0], bhi(au.z) * ghi[1]);
        ou.w = bpack(blo(au.w) * ghi[2], bhi(au.w) * ghi[3]);
        bf16x8 a; __builtin_memcpy(&a, &ou, 16);
#pragma unroll
        for (int nt = 0; nt < 4; ++nt) {
          const bf16x8 bb = *reinterpret_cast<const bf16x8*>(
              Tb + (16 * nt + (l & 15)) * 128 + (cb ^ fswz));
          acc[nt] = __builtin_amdgcn_mfma_f32_16x16x32_bf16(a, bb, acc[nt], 0, 0, 0);
        }
      }
    }
    __syncthreads();  // all waves done reading buf[(c+1)&1]
    if (c + 1 < kNC) {
      char* Tb = smem + ((c + 1) & 1) * ASZ;
#pragma unroll
      for (int j = 0; j < 4; ++j) {
        const int m = 4 * ct + j;
        const int off = m * 128 + ((8 * kt) ^ ((m & 7) << 4));
        uv2 wa; wa.x = bpack(v0[j], v1[j]); wa.y = bpack(v2[j], v3[j]);
        *reinterpret_cast<uv2*>(Tb + off) = wa;
      }
    }
  }

  // ---- G -> LDS ----
  // C/D layout: col = lane&15, row = (lane>>4)*4 + reg
  float* Gl = reinterpret_cast<float*>(smem);   // [80][GSTRIDE]
  float* hp = Gl + 80 * GSTRIDE;                // [64]
  constexpr float invP = 1.0f / 64.0f;
#pragma unroll
  for (int nt = 0; nt < 4; ++nt)
#pragma unroll
    for (int r = 0; r < 4; ++r)
      Gl[(16 * w + (l >> 4) * 4 + r) * GSTRIDE + 16 * nt + (l & 15)] =
          acc[nt][r] * invP;

  if (t < kP) hp[t] = yv;
  __syncthreads();

  // ---- phase 2: 16 steps, 4 threads per row; G row in registers ----
  const int m = t >> 2;        // 0..79
  const int part = t & 3;
  const fv4* Grow4 = reinterpret_cast<const fv4*>(Gl + m * GSTRIDE + part * 16);
  const fv4* hpp4  = reinterpret_cast<const fv4*>(hp + part * 16);
  const fv4 G0 = Grow4[0], G1 = Grow4[1], G2 = Grow4[2], G3 = Grow4[3];
  float hk = 0.f;
  constexpr float invL = 1.0f / kLS;
  for (int s = 0; s < kLS; ++s) {
    const fv4 h0 = hpp4[0], h1 = hpp4[1], h2 = hpp4[2], h3 = hpp4[3];
    float d0 = 0.f, d1 = 0.f, d2 = 0.f, d3 = 0.f;
#pragma unroll
    for (int i = 0; i < 4; ++i) {
      d0 = fmaf(G0[i], h0[i], d0);
      d1 = fmaf(G1[i], h1[i], d1);
      d2 = fmaf(G2[i], h2[i], d2);
      d3 = fmaf(G3[i], h3[i], d3);
    }
    float dot = (d0 + d1) + (d2 + d3);
    dot += __shfl_xor(dot, 1);
    dot += __shfl_xor(dot, 2);
    __syncthreads();  // all reads of hp for this step complete
    if (part == 0) {
      if (m < kP) hp[m] -= invL * dot;   // unique writer per m
      else        hk   += invL * dot;
    }
    __syncthreads();  // hp update visible for next step
  }
  if (part == 0 && m >= kP) out[b * kKK + (m - kP)] = hk;
}

}  // namespace

extern "C" void kernel_launch(void* const* d_in, const int* in_sizes, int n_in,
                              void* d_out, int out_size, void* d_ws, size_t ws_size,
                              hipStream_t stream) {
  const float* X     = (const float*)d_in[0];  // [512,1024,80]
  const float* y     = (const float*)d_in[1];  // [512,64]
  const float* gamma = (const float*)d_in[2];  // [1024]
  float* out = (float*)d_out;                  // [512,16]
  tcsf_kernel<<<dim3(kB), dim3(kThreads), 0, stream>>>(X, y, gamma, out);
}

// Round 13
// 36.820 us; speedup vs baseline: 1.0379x; 1.0379x over previous
//
#include <hip/hip_runtime.h>
#include <hip/hip_bf16.h>

// TiedCirculantSpectralFilter: B=512, D=1024, P=64, K=16, L_S=16
// Gram G[m,n] = sum_d X[d,m] * (gamma_d * X[d,n]) / 64  via bf16 MFMA,
// then 16 steps: hp <- hp - (1/16) A hp ; hk <- hk + (1/16) C hp.
//
// CHAMPION (r9, 36.5 us): r3 structure (320 thr / 5 waves, lockstep,
// 2 barriers/chunk, issue distance 1) plus:
//  - bf16 pack via scalar __float2bfloat16 casts (compiler fuses pairs into
//    v_cvt_pk_bf16_f32)
//  - phase 2: G row hoisted to registers before the step loop (step-invariant;
//    compiler couldn't prove no-alias vs hp writes -> was re-reading 16
//    ds_read_b32 x 16 steps). GSTRIDE=68 keeps 16B alignment so G and hp
//    move as b128; 17-bank row stride stays conflict-free.
// Attempted beyond this (all null or regressions): 1-barrier grouped staging
// (r4), write-swizzle + depth-2 (r5), producer/consumer waves (r6), deep
// prefetch (r7), issue-distance-2 (r10), B-tile-free gamma-in-reg (r12).
// Floor analysis: 167.8 MB mandatory / ~4.6 TB/s sustained ~= 36 us.

namespace {
typedef __attribute__((ext_vector_type(8))) short bf16x8;
typedef __attribute__((ext_vector_type(4))) float f32x4;
typedef __attribute__((ext_vector_type(4))) float fv4;
typedef __attribute__((ext_vector_type(2))) unsigned uv2;

constexpr int kB  = 512;
constexpr int kD  = 1024;
constexpr int kP  = 64;
constexpr int kKK = 16;
constexpr int kLS = 16;
constexpr int kThreads = 320;           // 5 waves
constexpr int kKc = 64;                 // d-rows per chunk
constexpr int kNC = kD / kKc;           // 16 chunks

constexpr int TB    = 4096;             // gamma f32[1024] at byte 0
constexpr int ASZ   = 80 * 128;         // A tile [80 m][64 k] bf16, swizzled
constexpr int BSZ   = 64 * 128;         // B tile [64 n][64 k] bf16, gamma-weighted
constexpr int BUFSZ = ASZ + BSZ;        // 18432
constexpr int LDS_BYTES = TB + 2 * BUFSZ;  // 40960
constexpr int GSTRIDE = 68;             // floats; 16B-aligned rows, odd bank stride

__device__ __forceinline__ unsigned bpack(float lo, float hi) {
  __hip_bfloat16 hl = __float2bfloat16(lo);
  __hip_bfloat16 hh = __float2bfloat16(hi);
  unsigned short ul, uh;
  __builtin_memcpy(&ul, &hl, 2);
  __builtin_memcpy(&uh, &hh, 2);
  return (unsigned)ul | ((unsigned)uh << 16);
}

__global__ void __launch_bounds__(kThreads)
tcsf_kernel(const float* __restrict__ X, const float* __restrict__ y,
            const float* __restrict__ gamma, float* __restrict__ out) {
  __shared__ __align__(16) char smem[LDS_BYTES];
  float* gs = reinterpret_cast<float*>(smem);

  const int t = threadIdx.x;
  const int b = blockIdx.x;
  const int l = t & 63;
  const int w = t >> 6;            // wave 0..4 -> m-rows 16w..16w+15

  float yv = 0.f;
  if (t < kP) yv = y[b * kP + t];
  for (int i = t; i < kD; i += kThreads) gs[i] = gamma[i];

  const fv4* Xg = reinterpret_cast<const fv4*>(X) + (size_t)b * (kD * 80 / 4);

  // staging decomposition: thread t handles k = 4*kt + i (i=0..3), m = 4*ct + j
  const int ct = t % 20;           // m-quad
  const int kt = t / 20;           // k-quad (0..15)

  f32x4 acc[4];
#pragma unroll
  for (int nt = 0; nt < 4; ++nt) acc[nt] = (f32x4)(0.f);

  fv4 v0, v1, v2, v3;
  fv4 g4;

  __syncthreads();  // gamma visible

  // ---- prologue: load + stage chunk 0 into buf 0 ----
  {
    v0 = Xg[(4 * kt) * 20 + ct];
    v1 = Xg[(4 * kt) * 20 + ct + 20];
    v2 = Xg[(4 * kt) * 20 + ct + 40];
    v3 = Xg[(4 * kt) * 20 + ct + 60];
    g4 = *reinterpret_cast<const fv4*>(gs + 4 * kt);
    char* Ab = smem + TB;
    char* Bb = Ab + ASZ;
#pragma unroll
    for (int j = 0; j < 4; ++j) {
      const int m = 4 * ct + j;
      const int off = m * 128 + ((8 * kt) ^ ((m & 7) << 4));
      uv2 wa; wa.x = bpack(v0[j], v1[j]); wa.y = bpack(v2[j], v3[j]);
      *reinterpret_cast<uv2*>(Ab + off) = wa;
      if (ct < 16) {
        uv2 wb; wb.x = bpack(g4[0] * v0[j], g4[1] * v1[j]);
        wb.y = bpack(g4[2] * v2[j], g4[3] * v3[j]);
        *reinterpret_cast<uv2*>(Bb + off) = wb;
      }
    }
  }

  // fragment read addressing (constant per thread)
  const int rA = 16 * w + (l & 15);
  const int colb = (l >> 4) * 16;
  const int fswz = (l & 7) << 4;   // rA&7 == l&7, rB&7 == l&7

  // ---- main loop over 16 chunks, double-buffered, 2 barriers/chunk ----
  for (int c = 0; c < kNC; ++c) {
    if (c + 1 < kNC) {  // issue next-chunk loads; latency hides under compute
      const int base = ((c + 1) * kKc + 4 * kt) * 20 + ct;
      v0 = Xg[base]; v1 = Xg[base + 20]; v2 = Xg[base + 40]; v3 = Xg[base + 60];
      g4 = *reinterpret_cast<const fv4*>(gs + (c + 1) * kKc + 4 * kt);
    }
    __syncthreads();  // buf[c&1] staging complete
    {
      const char* Ab = smem + TB + (c & 1) * BUFSZ;
      const char* Bb = Ab + ASZ;
#pragma unroll
      for (int ks = 0; ks < 2; ++ks) {
        const int cb = ks * 64 + colb;
        const bf16x8 a = *reinterpret_cast<const bf16x8*>(Ab + rA * 128 + (cb ^ fswz));
#pragma unroll
        for (int nt = 0; nt < 4; ++nt) {
          const bf16x8 bb = *reinterpret_cast<const bf16x8*>(
              Bb + (16 * nt + (l & 15)) * 128 + (cb ^ fswz));
          acc[nt] = __builtin_amdgcn_mfma_f32_16x16x32_bf16(a, bb, acc[nt], 0, 0, 0);
        }
      }
    }
    __syncthreads();  // all waves done reading buf[(c+1)&1]
    if (c + 1 < kNC) {
      char* Ab = smem + TB + ((c + 1) & 1) * BUFSZ;
      char* Bb = Ab + ASZ;
#pragma unroll
      for (int j = 0; j < 4; ++j) {
        const int m = 4 * ct + j;
        const int off = m * 128 + ((8 * kt) ^ ((m & 7) << 4));
        uv2 wa; wa.x = bpack(v0[j], v1[j]); wa.y = bpack(v2[j], v3[j]);
        *reinterpret_cast<uv2*>(Ab + off) = wa;
        if (ct < 16) {
          uv2 wb; wb.x = bpack(g4[0] * v0[j], g4[1] * v1[j]);
          wb.y = bpack(g4[2] * v2[j], g4[3] * v3[j]);
          *reinterpret_cast<uv2*>(Bb + off) = wb;
        }
      }
    }
  }

  // ---- G -> LDS ----
  // C/D layout: col = lane&15, row = (lane>>4)*4 + reg
  float* Gl = reinterpret_cast<float*>(smem + TB);  // [80][GSTRIDE]
  float* hp = Gl + 80 * GSTRIDE;                    // [64]
  constexpr float invP = 1.0f / 64.0f;
#pragma unroll
  for (int nt = 0; nt < 4; ++nt)
#pragma unroll
    for (int r = 0; r < 4; ++r)
      Gl[(16 * w + (l >> 4) * 4 + r) * GSTRIDE + 16 * nt + (l & 15)] =
          acc[nt][r] * invP;

  if (t < kP) hp[t] = yv;
  __syncthreads();

  // ---- phase 2: 16 steps, 4 threads per row; G row in registers ----
  const int m = t >> 2;        // 0..79
  const int part = t & 3;
  const fv4* Grow4 = reinterpret_cast<const fv4*>(Gl + m * GSTRIDE + part * 16);
  const fv4* hpp4  = reinterpret_cast<const fv4*>(hp + part * 16);
  const fv4 G0 = Grow4[0], G1 = Grow4[1], G2 = Grow4[2], G3 = Grow4[3];
  float hk = 0.f;
  constexpr float invL = 1.0f / kLS;
  for (int s = 0; s < kLS; ++s) {
    const fv4 h0 = hpp4[0], h1 = hpp4[1], h2 = hpp4[2], h3 = hpp4[3];
    float d0 = 0.f, d1 = 0.f, d2 = 0.f, d3 = 0.f;
#pragma unroll
    for (int i = 0; i < 4; ++i) {
      d0 = fmaf(G0[i], h0[i], d0);
      d1 = fmaf(G1[i], h1[i], d1);
      d2 = fmaf(G2[i], h2[i], d2);
      d3 = fmaf(G3[i], h3[i], d3);
    }
    float dot = (d0 + d1) + (d2 + d3);
    dot += __shfl_xor(dot, 1);
    dot += __shfl_xor(dot, 2);
    __syncthreads();  // all reads of hp for this step complete
    if (part == 0) {
      if (m < kP) hp[m] -= invL * dot;   // unique writer per m
      else        hk   += invL * dot;
    }
    __syncthreads();  // hp update visible for next step
  }
  if (part == 0 && m >= kP) out[b * kKK + (m - kP)] = hk;
}

}  // namespace

extern "C" void kernel_launch(void* const* d_in, const int* in_sizes, int n_in,
                              void* d_out, int out_size, void* d_ws, size_t ws_size,
                              hipStream_t stream) {
  const float* X     = (const float*)d_in[0];  // [512,1024,80]
  const float* y     = (const float*)d_in[1];  // [512,64]
  const float* gamma = (const float*)d_in[2];  // [1024]
  float* out = (float*)d_out;                  // [512,16]
  tcsf_kernel<<<dim3(kB), dim3(kThreads), 0, stream>>>(X, y, gamma, out);
}